// Round 8
// baseline (240.056 us; speedup 1.0000x reference)
//
#include <hip/hip_runtime.h>

#define NN 50000
#define NE 250000
#define NT 7813        // ceil(NE/32)

typedef __attribute__((ext_vector_type(8)))  short    s16x8;
typedef __attribute__((ext_vector_type(16))) float    f32x16;
typedef __attribute__((ext_vector_type(4)))  unsigned u32x4;
typedef __attribute__((ext_vector_type(4)))  int      i32x4;

__device__ __forceinline__ unsigned bf16r(float f) {
    unsigned u = __float_as_uint(f);
    return (u + 0x7fffu + ((u >> 16) & 1u)) >> 16;   // RNE
}
__device__ __forceinline__ unsigned pk2(float lo, float hi) {
    return (bf16r(hi) << 16) | bf16r(lo);
}
__device__ __forceinline__ short bfs(float f) {
    __bf16 b = (__bf16)f;
    return __builtin_bit_cast(short, b);
}
__device__ __forceinline__ float ulo(unsigned v) { return __uint_as_float(v << 16); }
__device__ __forceinline__ float uhi(unsigned v) { return __uint_as_float(v & 0xffff0000u); }

// ws layout (bytes):
//   w2pk @ 0        67584    (16896 u32)
//   hist @ 67584    200000
//   rowp @ 267584   200016
//   off  @ 467600   200000
//   blks @ 667600   1024
//   srcs @ 668624   1000064  (250016 int; low 50000 doubles as scan tmp)
//   easp @ 1668688  8000512  (250016 x 8 u32, bf16-pair ea rows, frag order)
//   xpk  @ 9669200  3200000  (50000 x 16 u32, bf16-pair x rows)
//   msgp @ 12869200 16001024 (250016 x 16 u32, bf16-pair msg rows)
//   total ~28.9 MB

// ---------------------------------------------------------------------------
// K1: pack w2ext=[w2;b2] B-fragment image; pack x to bf16 pairs; zero hist.
// ---------------------------------------------------------------------------
__global__ __launch_bounds__(256) void prep_kernel(
    const float* __restrict__ w2, const float* __restrict__ b2,
    const float* __restrict__ x, unsigned* __restrict__ w2pk,
    unsigned* __restrict__ xpk, int* __restrict__ hist)
{
    int g = blockIdx.x * 256 + threadIdx.x;
    if (g < 16896) {
        int s = g >> 8, l = (g >> 2) & 63, q = g & 3;
        int col = l & 31;
        int kk = s * 16 + (l >> 5) * 8 + 2 * q;
        float f0 = (kk < 1024) ? w2[(kk >> 5) * 1024 + (kk & 31) * 32 + col]
                               : b2[(kk - 1024) * 32 + col];
        int k1 = kk + 1;
        float f1 = (k1 < 1024) ? w2[(k1 >> 5) * 1024 + (k1 & 31) * 32 + col]
                               : b2[(k1 - 1024) * 32 + col];
        w2pk[g] = (bf16r(f1) << 16) | bf16r(f0);
    } else if (g < 16896 + 800000) {
        int i = g - 16896;
        int n = i >> 4, t = i & 15;
        xpk[i] = pk2(x[n * 32 + 2 * t], x[n * 32 + 2 * t + 1]);
    } else if (g < 16896 + 800000 + 12500) {
        int c = g - 16896 - 800000;
        ((i32x4*)hist)[c] = i32x4{0, 0, 0, 0};
    }
}

// K2: histogram of dst
__global__ __launch_bounds__(256) void hist_kernel(
    const int* __restrict__ ei, int* __restrict__ hist)
{
    int e = blockIdx.x * 256 + threadIdx.x;
    if (e < NE) atomicAdd(&hist[ei[NE + e]], 1);
}

__device__ __forceinline__ int wave_incl_scan(int v, int lane) {
    #pragma unroll
    for (int o = 1; o < 64; o <<= 1) {
        int t = __shfl_up(v, o);
        if (lane >= o) v += t;
    }
    return v;
}

// K3: per-block inclusive scan of hist -> tmp; block sums -> blks
__global__ __launch_bounds__(256) void scan_a(
    const int* __restrict__ hist, int* __restrict__ tmp, int* __restrict__ blks)
{
    int g = blockIdx.x * 256 + threadIdx.x;
    int lane = threadIdx.x & 63, w = threadIdx.x >> 6;
    int v = (g < NN) ? hist[g] : 0;
    v = wave_incl_scan(v, lane);
    __shared__ int ws[4];
    if (lane == 63) ws[w] = v;
    __syncthreads();
    int add = (w > 0 ? ws[0] : 0) + (w > 1 ? ws[1] : 0) + (w > 2 ? ws[2] : 0);
    v += add;
    if (g < NN) tmp[g] = v;
    if (threadIdx.x == 255) blks[blockIdx.x] = v;
}

// K4: exclusive scan of 196 block sums (in place)
__global__ __launch_bounds__(256) void scan_b(int* __restrict__ blks)
{
    int i = threadIdx.x;
    int lane = i & 63, w = i >> 6;
    int v0 = (i < 196) ? blks[i] : 0;
    int v = wave_incl_scan(v0, lane);
    __shared__ int ws[4];
    if (lane == 63) ws[w] = v;
    __syncthreads();
    int add = (w > 0 ? ws[0] : 0) + (w > 1 ? ws[1] : 0) + (w > 2 ? ws[2] : 0);
    if (i < 196) blks[i] = v + add - v0;   // exclusive
}

// K5: rowp[g] = off[g] = exclusive scan; rowp[NN] = NE
__global__ __launch_bounds__(256) void addback(
    const int* __restrict__ hist, const int* __restrict__ tmp,
    const int* __restrict__ blks, int* __restrict__ rowp, int* __restrict__ off)
{
    int g = blockIdx.x * 256 + threadIdx.x;
    if (g < NN) {
        int excl = blks[blockIdx.x] + tmp[g] - hist[g];
        rowp[g] = excl;
        off[g]  = excl;
    }
    if (g == 0) rowp[NN] = NE;
}

// K6: permute+pack: srcs[p] = src(e); easp[p] = bf16-pair ea row (frag order).
//     Absorbs ALL edge-order randomness at copy bandwidth.
__global__ __launch_bounds__(256) void scatter_kernel(
    const int* __restrict__ ei, const float* __restrict__ ea,
    int* __restrict__ off, int* __restrict__ srcs, unsigned* __restrict__ easp)
{
    int e = blockIdx.x * 256 + threadIdx.x;
    if (e < NE) {
        int s = ei[e];
        int d = ei[NE + e];
        int p = atomicAdd(&off[d], 1);
        srcs[p] = s;
        const float4* a4 = (const float4*)(ea + (size_t)e * 16);
        float4 A = a4[0], B = a4[1], C = a4[2], D = a4[3];
        u32x4* dst = (u32x4*)(easp + (size_t)p * 8);
        dst[0] = u32x4{pk2(A.x, A.y), pk2(A.z, A.w), pk2(B.x, B.y), pk2(B.z, B.w)};
        dst[1] = u32x4{pk2(C.x, C.y), pk2(C.z, C.w), pk2(D.x, D.y), pk2(D.z, D.w)};
    }
}

// ---------------------------------------------------------------------------
// K7: edge kernel — all-streamed memory. 256 blocks x 1024 thr (round-2's
//     proven clean-traffic config), 66 KB LDS, shfl-h, msgp plain stores.
// ---------------------------------------------------------------------------
__global__ __launch_bounds__(1024, 4) void edge_kernel(
    const unsigned* __restrict__ xpk, const int* __restrict__ srcs,
    const unsigned* __restrict__ easp, const float* __restrict__ w1,
    const float* __restrict__ b1, const unsigned* __restrict__ w2pk,
    unsigned* __restrict__ msgp)
{
    extern __shared__ unsigned sw2[];             // 66*256 dwords = 67584 B
    {
        const u32x4* srcp = (const u32x4*)w2pk;
        u32x4* dstp = (u32x4*)sw2;
        for (int c = threadIdx.x; c < 66 * 64; c += 1024) dstp[c] = srcp[c];
    }
    __syncthreads();

    const int lane = threadIdx.x & 63;
    const int wave = threadIdx.x >> 6;
    const int er0  = lane & 31;     // tile position (A/D row); hid col (B/D)
    const int half = lane >> 5;

    // w1 B-fragment (16x32): lane l -> w1[(l>>5)*8+j][l&31]
    s16x8 w1f;
    #pragma unroll
    for (int j = 0; j < 8; j++) w1f[j] = bfs(w1[(half * 8 + j) * 32 + er0]);
    float b1r[16];
    #pragma unroll
    for (int i = 0; i < 16; i++)
        b1r[i] = b1[(i & 3) + 8 * (i >> 2) + 4 * half];

    for (int tile = blockIdx.x * 16 + wave; tile < NT; tile += 4096) {
        const int B0  = tile * 32;
        const int pos = B0 + er0;
        const int pc  = pos < NE ? pos : NE - 1;
        const int src = srcs[pc];

        // x (bf16-pair, streamed-layout gather): lane needs pair-cols
        // [half*4, half*4+4) and [8+half*4, ...+4)
        u32x4 xl4 = *(const u32x4*)(xpk + src * 16 + half * 4);
        u32x4 xh4 = *(const u32x4*)(xpk + src * 16 + 8 + half * 4);
        float xlo[8], xhi[8];
        #pragma unroll
        for (int q = 0; q < 4; q++) {
            xlo[2*q] = ulo(xl4[q]); xlo[2*q+1] = uhi(xl4[q]);
            xhi[2*q] = ulo(xh4[q]); xhi[2*q+1] = uhi(xh4[q]);
        }

        // ea A-fragment: direct 16-B load (pre-packed in fragment order)
        s16x8 eaf = *(const s16x8*)(easp + (size_t)pc * 8 + half * 4);

        // hT[k][e] = (ea @ w1)^T via operand swap; bias + relu
        f32x16 hc = {};
        hc = __builtin_amdgcn_mfma_f32_32x32x16_bf16(w1f, eaf, hc, 0, 0, 0);
        float X16[16];
        #pragma unroll
        for (int i = 0; i < 16; i++) X16[i] = fmaxf(hc[i] + b1r[i], 0.f);

        f32x16 acc = {};
        #pragma unroll
        for (int i = 0; i < 16; i++) {
            const float other = __shfl_xor(X16[i], 32);
            const float hA = half ? other : X16[i];
            const float hB = half ? X16[i] : other;
            const int kA = (i & 3) + 8 * (i >> 2);
            {
                s16x8 alo, ahi;
                #pragma unroll
                for (int j = 0; j < 8; j++) alo[j] = bfs(hA * xlo[j]);
                #pragma unroll
                for (int j = 0; j < 8; j++) ahi[j] = bfs(hA * xhi[j]);
                s16x8 blo = *(const s16x8*)(sw2 + (2 * kA)     * 256 + lane * 4);
                s16x8 bhi = *(const s16x8*)(sw2 + (2 * kA + 1) * 256 + lane * 4);
                acc = __builtin_amdgcn_mfma_f32_32x32x16_bf16(alo, blo, acc, 0, 0, 0);
                acc = __builtin_amdgcn_mfma_f32_32x32x16_bf16(ahi, bhi, acc, 0, 0, 0);
            }
            {
                const int kB = kA + 4;
                s16x8 alo, ahi;
                #pragma unroll
                for (int j = 0; j < 8; j++) alo[j] = bfs(hB * xlo[j]);
                #pragma unroll
                for (int j = 0; j < 8; j++) ahi[j] = bfs(hB * xhi[j]);
                s16x8 blo = *(const s16x8*)(sw2 + (2 * kB)     * 256 + lane * 4);
                s16x8 bhi = *(const s16x8*)(sw2 + (2 * kB + 1) * 256 + lane * 4);
                acc = __builtin_amdgcn_mfma_f32_32x32x16_bf16(alo, blo, acc, 0, 0, 0);
                acc = __builtin_amdgcn_mfma_f32_32x32x16_bf16(ahi, bhi, acc, 0, 0, 0);
            }
        }
        // b2 rows (h == 1): steps 64, 65
        {
            s16x8 alo, ahi;
            #pragma unroll
            for (int j = 0; j < 8; j++) alo[j] = bfs(xlo[j]);
            #pragma unroll
            for (int j = 0; j < 8; j++) ahi[j] = bfs(xhi[j]);
            s16x8 b64 = *(const s16x8*)(sw2 + 64 * 256 + lane * 4);
            s16x8 b65 = *(const s16x8*)(sw2 + 65 * 256 + lane * 4);
            acc = __builtin_amdgcn_mfma_f32_32x32x16_bf16(alo, b64, acc, 0, 0, 0);
            acc = __builtin_amdgcn_mfma_f32_32x32x16_bf16(ahi, b65, acc, 0, 0, 0);
        }

        // streamed store: D row r -> sorted position p; pack hid pair
        #pragma unroll
        for (int r = 0; r < 16; r++) {
            const int p  = B0 + (r & 3) + 8 * (r >> 2) + 4 * half;
            const float partner = __shfl_xor(acc[r], 1);
            if (!(er0 & 1) && p < NE) {
                unsigned pkv = (bf16r(partner) << 16) | bf16r(acc[r]);
                msgp[(size_t)p * 16 + (er0 >> 1)] = pkv;
            }
        }
    }
}

// ---------------------------------------------------------------------------
// K8: node kernel — contiguous gather of sorted msg run, mean, epilogue.
// ---------------------------------------------------------------------------
__global__ __launch_bounds__(256) void node_kernel(
    const float* __restrict__ x, const float* __restrict__ root,
    const float* __restrict__ bias_conv, const float* __restrict__ w3,
    const float* __restrict__ b3, const int* __restrict__ rowp,
    const unsigned* __restrict__ msgp, float* __restrict__ out)
{
    __shared__ float xs[8][32];
    __shared__ float ms[8][32];
    const int li = threadIdx.x >> 5, hid = threadIdx.x & 31;
    const int n = blockIdx.x * 8 + li;

    xs[li][hid] = x[n * 32 + hid];
    __syncthreads();

    float xr = 0.f;
    #pragma unroll
    for (int t = 0; t < 32; t++) xr += xs[li][t] * root[t * 32 + hid];

    const int r0 = rowp[n], r1 = rowp[n + 1];
    float m = 0.f;
    for (int p = r0; p < r1; ++p) {
        unsigned v = msgp[(size_t)p * 16 + (hid >> 1)];
        m += (hid & 1) ? uhi(v) : ulo(v);
    }
    float ic = 1.0f / (float)(r1 > r0 ? r1 - r0 : 1);
    m = m * ic + xr + bias_conv[hid];
    ms[li][hid] = m;
    __syncthreads();

    float o = b3[hid];
    #pragma unroll
    for (int t = 0; t < 32; t++) {
        o += xs[li][t] * w3[t * 32 + hid];
        o += ms[li][t] * w3[(32 + t) * 32 + hid];
    }
    out[n * 32 + hid] = fmaxf(o, 0.f);
}

// ---------------------------------------------------------------------------
extern "C" void kernel_launch(void* const* d_in, const int* in_sizes, int n_in,
                              void* d_out, int out_size, void* d_ws, size_t ws_size,
                              hipStream_t stream) {
    const float* x    = (const float*)d_in[0];
    const int*   ei   = (const int*)  d_in[1];
    const float* ea   = (const float*)d_in[2];
    const float* w1   = (const float*)d_in[3];
    const float* b1   = (const float*)d_in[4];
    const float* w2   = (const float*)d_in[5];
    const float* b2   = (const float*)d_in[6];
    const float* root = (const float*)d_in[7];
    const float* bc   = (const float*)d_in[8];
    const float* w3   = (const float*)d_in[9];
    const float* b3   = (const float*)d_in[10];

    char* ws = (char*)d_ws;
    unsigned* w2pk = (unsigned*)(ws + 0);
    int*      hist = (int*)(ws + 67584);
    int*      rowp = (int*)(ws + 267584);
    int*      off  = (int*)(ws + 467600);
    int*      blks = (int*)(ws + 667600);
    int*      srcs = (int*)(ws + 668624);
    unsigned* easp = (unsigned*)(ws + 1668688);
    unsigned* xpk  = (unsigned*)(ws + 9669200);
    unsigned* msgp = (unsigned*)(ws + 12869200);
    int*      tmp  = srcs;                       // scan scratch (pre-scatter)
    float*    out  = (float*)d_out;

    prep_kernel<<<3240, 256, 0, stream>>>(w2, b2, x, w2pk, xpk, hist);
    hist_kernel<<<977, 256, 0, stream>>>(ei, hist);
    scan_a<<<196, 256, 0, stream>>>(hist, tmp, blks);
    scan_b<<<1, 256, 0, stream>>>(blks);
    addback<<<196, 256, 0, stream>>>(hist, tmp, blks, rowp, off);
    scatter_kernel<<<977, 256, 0, stream>>>(ei, ea, off, srcs, easp);

    const int lds_bytes = 66 * 1024;             // 67584
    hipFuncSetAttribute((const void*)edge_kernel,
                        hipFuncAttributeMaxDynamicSharedMemorySize, lds_bytes);
    edge_kernel<<<256, 1024, lds_bytes, stream>>>(xpk, srcs, easp, w1, b1,
                                                  w2pk, msgp);

    node_kernel<<<NN / 8, 256, 0, stream>>>(x, root, bc, w3, b3, rowp, msgp, out);
}

// Round 9
// 190.775 us; speedup vs baseline: 1.2583x; 1.2583x over previous
//
#include <hip/hip_runtime.h>

#define NN 50000
#define NE 250000
#define NT 7813        // ceil(NE/32)
#define NBLK 512

typedef __attribute__((ext_vector_type(8)))  short    s16x8;
typedef __attribute__((ext_vector_type(16))) float    f32x16;
typedef __attribute__((ext_vector_type(4)))  unsigned u32x4;
typedef __attribute__((ext_vector_type(4)))  int      i32x4;

__device__ __forceinline__ unsigned bf16r(float f) {
    unsigned u = __float_as_uint(f);
    return (u + 0x7fffu + ((u >> 16) & 1u)) >> 16;   // RNE
}
__device__ __forceinline__ unsigned pk2(float lo, float hi) {
    return (bf16r(hi) << 16) | bf16r(lo);
}
__device__ __forceinline__ short bfs(float f) {
    __bf16 b = (__bf16)f;
    return __builtin_bit_cast(short, b);
}
__device__ __forceinline__ float ulo(unsigned v) { return __uint_as_float(v << 16); }
__device__ __forceinline__ float uhi(unsigned v) { return __uint_as_float(v & 0xffff0000u); }

// ws layout (bytes):
//   w2pk @ 0        67584    (16896 u32)
//   hist @ 67584    200000
//   rowp @ 267584   200016
//   off  @ 467600   200000
//   blks @ 667600   1024
//   srcs @ 668624   1000064  (250016 int; low 50000 doubles as scan tmp)
//   easp @ 1668688  8000512  (250016 x 8 u32, bf16-pair ea rows, frag order)
//   xpk  @ 9669200  3200000  (50000 x 16 u32, bf16-pair x rows)
//   msgp @ 12869200 16001024 (250016 x 16 u32, bf16-pair msg rows)

// ---------------------------------------------------------------------------
// K1: pack w2ext=[w2;b2] B-fragment image; pack x to bf16 pairs; zero hist.
// ---------------------------------------------------------------------------
__global__ __launch_bounds__(256) void prep_kernel(
    const float* __restrict__ w2, const float* __restrict__ b2,
    const float* __restrict__ x, unsigned* __restrict__ w2pk,
    unsigned* __restrict__ xpk, int* __restrict__ hist)
{
    int g = blockIdx.x * 256 + threadIdx.x;
    if (g < 16896) {
        int s = g >> 8, l = (g >> 2) & 63, q = g & 3;
        int col = l & 31;
        int kk = s * 16 + (l >> 5) * 8 + 2 * q;
        float f0 = (kk < 1024) ? w2[(kk >> 5) * 1024 + (kk & 31) * 32 + col]
                               : b2[(kk - 1024) * 32 + col];
        int k1 = kk + 1;
        float f1 = (k1 < 1024) ? w2[(k1 >> 5) * 1024 + (k1 & 31) * 32 + col]
                               : b2[(k1 - 1024) * 32 + col];
        w2pk[g] = (bf16r(f1) << 16) | bf16r(f0);
    } else if (g < 16896 + 800000) {
        int i = g - 16896;
        int n = i >> 4, t = i & 15;
        xpk[i] = pk2(x[n * 32 + 2 * t], x[n * 32 + 2 * t + 1]);
    } else if (g < 16896 + 800000 + 12500) {
        int c = g - 16896 - 800000;
        ((i32x4*)hist)[c] = i32x4{0, 0, 0, 0};
    }
}

// K2: histogram of dst
__global__ __launch_bounds__(256) void hist_kernel(
    const int* __restrict__ ei, int* __restrict__ hist)
{
    int e = blockIdx.x * 256 + threadIdx.x;
    if (e < NE) atomicAdd(&hist[ei[NE + e]], 1);
}

__device__ __forceinline__ int wave_incl_scan(int v, int lane) {
    #pragma unroll
    for (int o = 1; o < 64; o <<= 1) {
        int t = __shfl_up(v, o);
        if (lane >= o) v += t;
    }
    return v;
}

// K3: per-block inclusive scan of hist -> tmp; block sums -> blks
__global__ __launch_bounds__(256) void scan_a(
    const int* __restrict__ hist, int* __restrict__ tmp, int* __restrict__ blks)
{
    int g = blockIdx.x * 256 + threadIdx.x;
    int lane = threadIdx.x & 63, w = threadIdx.x >> 6;
    int v = (g < NN) ? hist[g] : 0;
    v = wave_incl_scan(v, lane);
    __shared__ int ws[4];
    if (lane == 63) ws[w] = v;
    __syncthreads();
    int add = (w > 0 ? ws[0] : 0) + (w > 1 ? ws[1] : 0) + (w > 2 ? ws[2] : 0);
    v += add;
    if (g < NN) tmp[g] = v;
    if (threadIdx.x == 255) blks[blockIdx.x] = v;
}

// K4: exclusive scan of 196 block sums (in place)
__global__ __launch_bounds__(256) void scan_b(int* __restrict__ blks)
{
    int i = threadIdx.x;
    int lane = i & 63, w = i >> 6;
    int v0 = (i < 196) ? blks[i] : 0;
    int v = wave_incl_scan(v0, lane);
    __shared__ int ws[4];
    if (lane == 63) ws[w] = v;
    __syncthreads();
    int add = (w > 0 ? ws[0] : 0) + (w > 1 ? ws[1] : 0) + (w > 2 ? ws[2] : 0);
    if (i < 196) blks[i] = v + add - v0;   // exclusive
}

// K5: rowp[g] = off[g] = exclusive scan; rowp[NN] = NE
__global__ __launch_bounds__(256) void addback(
    const int* __restrict__ hist, const int* __restrict__ tmp,
    const int* __restrict__ blks, int* __restrict__ rowp, int* __restrict__ off)
{
    int g = blockIdx.x * 256 + threadIdx.x;
    if (g < NN) {
        int excl = blks[blockIdx.x] + tmp[g] - hist[g];
        rowp[g] = excl;
        off[g]  = excl;
    }
    if (g == 0) rowp[NN] = NE;
}

// K6: permute+pack: srcs[p] = src(e); easp[p] = bf16-pair ea row (frag order)
__global__ __launch_bounds__(256) void scatter_kernel(
    const int* __restrict__ ei, const float* __restrict__ ea,
    int* __restrict__ off, int* __restrict__ srcs, unsigned* __restrict__ easp)
{
    int e = blockIdx.x * 256 + threadIdx.x;
    if (e < NE) {
        int s = ei[e];
        int d = ei[NE + e];
        int p = atomicAdd(&off[d], 1);
        srcs[p] = s;
        const float4* a4 = (const float4*)(ea + (size_t)e * 16);
        float4 A = a4[0], B = a4[1], C = a4[2], D = a4[3];
        u32x4* dst = (u32x4*)(easp + (size_t)p * 8);
        dst[0] = u32x4{pk2(A.x, A.y), pk2(A.z, A.w), pk2(B.x, B.y), pk2(B.z, B.w)};
        dst[1] = u32x4{pk2(C.x, C.y), pk2(C.z, C.w), pk2(D.x, D.y), pk2(D.z, D.w)};
    }
}

// ---------------------------------------------------------------------------
// K7: edge kernel — identical memory structure to round 8, but spill-free
//     launch config: 512 thr, launch_bounds(512,3) -> VGPR cap ~170 (live
//     set ~130). X16 aliased into hc (in-place relu) to trim 16 regs.
// ---------------------------------------------------------------------------
__global__ __launch_bounds__(512, 3) void edge_kernel(
    const unsigned* __restrict__ xpk, const int* __restrict__ srcs,
    const unsigned* __restrict__ easp, const float* __restrict__ w1,
    const float* __restrict__ b1, const unsigned* __restrict__ w2pk,
    unsigned* __restrict__ msgp)
{
    extern __shared__ unsigned sw2[];             // 66*256 dwords = 67584 B
    {
        const u32x4* srcp = (const u32x4*)w2pk;
        u32x4* dstp = (u32x4*)sw2;
        for (int c = threadIdx.x; c < 66 * 64; c += 512) dstp[c] = srcp[c];
    }
    __syncthreads();

    const int lane = threadIdx.x & 63;
    const int wave = threadIdx.x >> 6;
    const int er0  = lane & 31;     // tile position (A/D row); hid col (B/D)
    const int half = lane >> 5;

    // w1 B-fragment (16x32): lane l -> w1[(l>>5)*8+j][l&31]
    s16x8 w1f;
    #pragma unroll
    for (int j = 0; j < 8; j++) w1f[j] = bfs(w1[(half * 8 + j) * 32 + er0]);
    float b1r[16];
    #pragma unroll
    for (int i = 0; i < 16; i++)
        b1r[i] = b1[(i & 3) + 8 * (i >> 2) + 4 * half];

    for (int tile = blockIdx.x * 8 + wave; tile < NT; tile += NBLK * 8) {
        const int B0  = tile * 32;
        const int pos = B0 + er0;
        const int pc  = pos < NE ? pos : NE - 1;
        const int src = srcs[pc];

        // x (bf16-pair rows): lane needs pair-cols [half*4,+4) and [8+half*4,+4)
        u32x4 xl4 = *(const u32x4*)(xpk + src * 16 + half * 4);
        u32x4 xh4 = *(const u32x4*)(xpk + src * 16 + 8 + half * 4);
        float xlo[8], xhi[8];
        #pragma unroll
        for (int q = 0; q < 4; q++) {
            xlo[2*q] = ulo(xl4[q]); xlo[2*q+1] = uhi(xl4[q]);
            xhi[2*q] = ulo(xh4[q]); xhi[2*q+1] = uhi(xh4[q]);
        }

        // ea A-fragment: direct 16-B load (pre-packed in fragment order)
        s16x8 eaf = *(const s16x8*)(easp + (size_t)pc * 8 + half * 4);

        // hT[k][e] = (ea @ w1)^T via operand swap; bias + relu IN PLACE
        f32x16 hc = {};
        hc = __builtin_amdgcn_mfma_f32_32x32x16_bf16(w1f, eaf, hc, 0, 0, 0);
        #pragma unroll
        for (int i = 0; i < 16; i++) hc[i] = fmaxf(hc[i] + b1r[i], 0.f);

        f32x16 acc = {};
        #pragma unroll
        for (int i = 0; i < 16; i++) {
            const float other = __shfl_xor(hc[i], 32);
            const float hA = half ? other : hc[i];
            const float hB = half ? hc[i] : other;
            const int kA = (i & 3) + 8 * (i >> 2);
            {
                s16x8 alo, ahi;
                #pragma unroll
                for (int j = 0; j < 8; j++) alo[j] = bfs(hA * xlo[j]);
                #pragma unroll
                for (int j = 0; j < 8; j++) ahi[j] = bfs(hA * xhi[j]);
                s16x8 blo = *(const s16x8*)(sw2 + (2 * kA)     * 256 + lane * 4);
                s16x8 bhi = *(const s16x8*)(sw2 + (2 * kA + 1) * 256 + lane * 4);
                acc = __builtin_amdgcn_mfma_f32_32x32x16_bf16(alo, blo, acc, 0, 0, 0);
                acc = __builtin_amdgcn_mfma_f32_32x32x16_bf16(ahi, bhi, acc, 0, 0, 0);
            }
            {
                const int kB = kA + 4;
                s16x8 alo, ahi;
                #pragma unroll
                for (int j = 0; j < 8; j++) alo[j] = bfs(hB * xlo[j]);
                #pragma unroll
                for (int j = 0; j < 8; j++) ahi[j] = bfs(hB * xhi[j]);
                s16x8 blo = *(const s16x8*)(sw2 + (2 * kB)     * 256 + lane * 4);
                s16x8 bhi = *(const s16x8*)(sw2 + (2 * kB + 1) * 256 + lane * 4);
                acc = __builtin_amdgcn_mfma_f32_32x32x16_bf16(alo, blo, acc, 0, 0, 0);
                acc = __builtin_amdgcn_mfma_f32_32x32x16_bf16(ahi, bhi, acc, 0, 0, 0);
            }
        }
        // b2 rows (h == 1): steps 64, 65
        {
            s16x8 alo, ahi;
            #pragma unroll
            for (int j = 0; j < 8; j++) alo[j] = bfs(xlo[j]);
            #pragma unroll
            for (int j = 0; j < 8; j++) ahi[j] = bfs(xhi[j]);
            s16x8 b64 = *(const s16x8*)(sw2 + 64 * 256 + lane * 4);
            s16x8 b65 = *(const s16x8*)(sw2 + 65 * 256 + lane * 4);
            acc = __builtin_amdgcn_mfma_f32_32x32x16_bf16(alo, b64, acc, 0, 0, 0);
            acc = __builtin_amdgcn_mfma_f32_32x32x16_bf16(ahi, b65, acc, 0, 0, 0);
        }

        // streamed store: D row r -> sorted position p; pack hid pair
        #pragma unroll
        for (int r = 0; r < 16; r++) {
            const int p  = B0 + (r & 3) + 8 * (r >> 2) + 4 * half;
            const float partner = __shfl_xor(acc[r], 1);
            if (!(er0 & 1) && p < NE) {
                unsigned pkv = (bf16r(partner) << 16) | bf16r(acc[r]);
                msgp[(size_t)p * 16 + (er0 >> 1)] = pkv;
            }
        }
    }
}

// ---------------------------------------------------------------------------
// K8: node kernel — contiguous gather of sorted msg run, mean, epilogue.
// ---------------------------------------------------------------------------
__global__ __launch_bounds__(256) void node_kernel(
    const float* __restrict__ x, const float* __restrict__ root,
    const float* __restrict__ bias_conv, const float* __restrict__ w3,
    const float* __restrict__ b3, const int* __restrict__ rowp,
    const unsigned* __restrict__ msgp, float* __restrict__ out)
{
    __shared__ float xs[8][32];
    __shared__ float ms[8][32];
    const int li = threadIdx.x >> 5, hid = threadIdx.x & 31;
    const int n = blockIdx.x * 8 + li;

    xs[li][hid] = x[n * 32 + hid];
    __syncthreads();

    float xr = 0.f;
    #pragma unroll
    for (int t = 0; t < 32; t++) xr += xs[li][t] * root[t * 32 + hid];

    const int r0 = rowp[n], r1 = rowp[n + 1];
    float m = 0.f;
    for (int p = r0; p < r1; ++p) {
        unsigned v = msgp[(size_t)p * 16 + (hid >> 1)];
        m += (hid & 1) ? uhi(v) : ulo(v);
    }
    float ic = 1.0f / (float)(r1 > r0 ? r1 - r0 : 1);
    m = m * ic + xr + bias_conv[hid];
    ms[li][hid] = m;
    __syncthreads();

    float o = b3[hid];
    #pragma unroll
    for (int t = 0; t < 32; t++) {
        o += xs[li][t] * w3[t * 32 + hid];
        o += ms[li][t] * w3[(32 + t) * 32 + hid];
    }
    out[n * 32 + hid] = fmaxf(o, 0.f);
}

// ---------------------------------------------------------------------------
extern "C" void kernel_launch(void* const* d_in, const int* in_sizes, int n_in,
                              void* d_out, int out_size, void* d_ws, size_t ws_size,
                              hipStream_t stream) {
    const float* x    = (const float*)d_in[0];
    const int*   ei   = (const int*)  d_in[1];
    const float* ea   = (const float*)d_in[2];
    const float* w1   = (const float*)d_in[3];
    const float* b1   = (const float*)d_in[4];
    const float* w2   = (const float*)d_in[5];
    const float* b2   = (const float*)d_in[6];
    const float* root = (const float*)d_in[7];
    const float* bc   = (const float*)d_in[8];
    const float* w3   = (const float*)d_in[9];
    const float* b3   = (const float*)d_in[10];

    char* ws = (char*)d_ws;
    unsigned* w2pk = (unsigned*)(ws + 0);
    int*      hist = (int*)(ws + 67584);
    int*      rowp = (int*)(ws + 267584);
    int*      off  = (int*)(ws + 467600);
    int*      blks = (int*)(ws + 667600);
    int*      srcs = (int*)(ws + 668624);
    unsigned* easp = (unsigned*)(ws + 1668688);
    unsigned* xpk  = (unsigned*)(ws + 9669200);
    unsigned* msgp = (unsigned*)(ws + 12869200);
    int*      tmp  = srcs;                       // scan scratch (pre-scatter)
    float*    out  = (float*)d_out;

    prep_kernel<<<3240, 256, 0, stream>>>(w2, b2, x, w2pk, xpk, hist);
    hist_kernel<<<977, 256, 0, stream>>>(ei, hist);
    scan_a<<<196, 256, 0, stream>>>(hist, tmp, blks);
    scan_b<<<1, 256, 0, stream>>>(blks);
    addback<<<196, 256, 0, stream>>>(hist, tmp, blks, rowp, off);
    scatter_kernel<<<977, 256, 0, stream>>>(ei, ea, off, srcs, easp);

    const int lds_bytes = 66 * 1024;             // 67584
    hipFuncSetAttribute((const void*)edge_kernel,
                        hipFuncAttributeMaxDynamicSharedMemorySize, lds_bytes);
    edge_kernel<<<NBLK, 512, lds_bytes, stream>>>(xpk, srcs, easp, w1, b1,
                                                  w2pk, msgp);

    node_kernel<<<NN / 8, 256, 0, stream>>>(x, root, bc, w3, b3, rowp, msgp, out);
}

// Round 10
// 106.848 us; speedup vs baseline: 2.2467x; 1.7855x over previous
//
#include <hip/hip_runtime.h>

#define NN 50000
#define NE 250000
#define NT 7813        // ceil(NE/32)

typedef __attribute__((ext_vector_type(8)))  short    s16x8;
typedef __attribute__((ext_vector_type(16))) float    f32x16;
typedef __attribute__((ext_vector_type(4)))  unsigned u32x4;
typedef __attribute__((ext_vector_type(4)))  int      i32x4;

__device__ __forceinline__ unsigned bf16r(float f) {
    unsigned u = __float_as_uint(f);
    return (u + 0x7fffu + ((u >> 16) & 1u)) >> 16;   // RNE
}
__device__ __forceinline__ unsigned pk2(float lo, float hi) {
    return (bf16r(hi) << 16) | bf16r(lo);
}
__device__ __forceinline__ short bfs(float f) {
    __bf16 b = (__bf16)f;
    return __builtin_bit_cast(short, b);
}
__device__ __forceinline__ float ulo(unsigned v) { return __uint_as_float(v << 16); }
__device__ __forceinline__ float uhi(unsigned v) { return __uint_as_float(v & 0xffff0000u); }

// ws layout (bytes):
//   w2pk @ 0        67584    (16896 u32)
//   hist @ 67584    200000
//   rowp @ 267584   200016
//   off  @ 467600   200000
//   blks @ 667600   1024
//   srcs @ 668624   1000064  (250016 int; low 50000 doubles as scan tmp)
//   easp @ 1668688  8000512  (250016 x 8 u32, bf16-pair ea rows, frag order)
//   xpk  @ 9669200  3200000  (50000 x 16 u32, bf16-pair x rows)
//   msgp @ 12869200 16001024 (250016 x 16 u32, bf16-pair msg rows)

// ---------------------------------------------------------------------------
// K1: pack w2ext=[w2;b2] B-fragment image; pack x to bf16 pairs; zero hist.
// ---------------------------------------------------------------------------
__global__ __launch_bounds__(256) void prep_kernel(
    const float* __restrict__ w2, const float* __restrict__ b2,
    const float* __restrict__ x, unsigned* __restrict__ w2pk,
    unsigned* __restrict__ xpk, int* __restrict__ hist)
{
    int g = blockIdx.x * 256 + threadIdx.x;
    if (g < 16896) {
        int s = g >> 8, l = (g >> 2) & 63, q = g & 3;
        int col = l & 31;
        int kk = s * 16 + (l >> 5) * 8 + 2 * q;
        float f0 = (kk < 1024) ? w2[(kk >> 5) * 1024 + (kk & 31) * 32 + col]
                               : b2[(kk - 1024) * 32 + col];
        int k1 = kk + 1;
        float f1 = (k1 < 1024) ? w2[(k1 >> 5) * 1024 + (k1 & 31) * 32 + col]
                               : b2[(k1 - 1024) * 32 + col];
        w2pk[g] = (bf16r(f1) << 16) | bf16r(f0);
    } else if (g < 16896 + 800000) {
        int i = g - 16896;
        int n = i >> 4, t = i & 15;
        xpk[i] = pk2(x[n * 32 + 2 * t], x[n * 32 + 2 * t + 1]);
    } else if (g < 16896 + 800000 + 12500) {
        int c = g - 16896 - 800000;
        ((i32x4*)hist)[c] = i32x4{0, 0, 0, 0};
    }
}

// K2: histogram of dst
__global__ __launch_bounds__(256) void hist_kernel(
    const int* __restrict__ ei, int* __restrict__ hist)
{
    int e = blockIdx.x * 256 + threadIdx.x;
    if (e < NE) atomicAdd(&hist[ei[NE + e]], 1);
}

__device__ __forceinline__ int wave_incl_scan(int v, int lane) {
    #pragma unroll
    for (int o = 1; o < 64; o <<= 1) {
        int t = __shfl_up(v, o);
        if (lane >= o) v += t;
    }
    return v;
}

// K3: per-block inclusive scan of hist -> tmp; block sums -> blks
__global__ __launch_bounds__(256) void scan_a(
    const int* __restrict__ hist, int* __restrict__ tmp, int* __restrict__ blks)
{
    int g = blockIdx.x * 256 + threadIdx.x;
    int lane = threadIdx.x & 63, w = threadIdx.x >> 6;
    int v = (g < NN) ? hist[g] : 0;
    v = wave_incl_scan(v, lane);
    __shared__ int ws[4];
    if (lane == 63) ws[w] = v;
    __syncthreads();
    int add = (w > 0 ? ws[0] : 0) + (w > 1 ? ws[1] : 0) + (w > 2 ? ws[2] : 0);
    v += add;
    if (g < NN) tmp[g] = v;
    if (threadIdx.x == 255) blks[blockIdx.x] = v;
}

// K4: exclusive scan of 196 block sums (in place)
__global__ __launch_bounds__(256) void scan_b(int* __restrict__ blks)
{
    int i = threadIdx.x;
    int lane = i & 63, w = i >> 6;
    int v0 = (i < 196) ? blks[i] : 0;
    int v = wave_incl_scan(v0, lane);
    __shared__ int ws[4];
    if (lane == 63) ws[w] = v;
    __syncthreads();
    int add = (w > 0 ? ws[0] : 0) + (w > 1 ? ws[1] : 0) + (w > 2 ? ws[2] : 0);
    if (i < 196) blks[i] = v + add - v0;   // exclusive
}

// K5: rowp[g] = off[g] = exclusive scan; rowp[NN] = NE
__global__ __launch_bounds__(256) void addback(
    const int* __restrict__ hist, const int* __restrict__ tmp,
    const int* __restrict__ blks, int* __restrict__ rowp, int* __restrict__ off)
{
    int g = blockIdx.x * 256 + threadIdx.x;
    if (g < NN) {
        int excl = blks[blockIdx.x] + tmp[g] - hist[g];
        rowp[g] = excl;
        off[g]  = excl;
    }
    if (g == 0) rowp[NN] = NE;
}

// K6: permute+pack: srcs[p] = src(e); easp[p] = bf16-pair ea row (frag order)
__global__ __launch_bounds__(256) void scatter_kernel(
    const int* __restrict__ ei, const float* __restrict__ ea,
    int* __restrict__ off, int* __restrict__ srcs, unsigned* __restrict__ easp)
{
    int e = blockIdx.x * 256 + threadIdx.x;
    if (e < NE) {
        int s = ei[e];
        int d = ei[NE + e];
        int p = atomicAdd(&off[d], 1);
        srcs[p] = s;
        const float4* a4 = (const float4*)(ea + (size_t)e * 16);
        float4 A = a4[0], B = a4[1], C = a4[2], D = a4[3];
        u32x4* dst = (u32x4*)(easp + (size_t)p * 8);
        dst[0] = u32x4{pk2(A.x, A.y), pk2(A.z, A.w), pk2(B.x, B.y), pk2(B.z, B.w)};
        dst[1] = u32x4{pk2(C.x, C.y), pk2(C.z, C.w), pk2(D.x, D.y), pk2(D.z, D.w)};
    }
}

// ---------------------------------------------------------------------------
// K7: edge kernel — ROUND-2 execution structure (proven VGPR=48, spill-free,
//     clean 21/39 MB traffic) + streamed inputs + plain msgp stores.
//     h = mfma(eaf, w1f) -> D[e][k], bias b1[er0] (1 reg), h via per-wave LDS.
// ---------------------------------------------------------------------------
__global__ __launch_bounds__(1024, 4) void edge_kernel(
    const unsigned* __restrict__ xpk, const int* __restrict__ srcs,
    const unsigned* __restrict__ easp, const float* __restrict__ w1,
    const float* __restrict__ b1, const unsigned* __restrict__ w2pk,
    unsigned* __restrict__ msgp)
{
    extern __shared__ char smem[];
    unsigned* sw2 = (unsigned*)smem;              // 67584 B
    {
        const u32x4* srcp = (const u32x4*)w2pk;
        u32x4* dstp = (u32x4*)sw2;
        for (int c = threadIdx.x; c < 66 * 64; c += 1024) dstp[c] = srcp[c];
    }
    __syncthreads();

    const int lane = threadIdx.x & 63;
    const int wave = threadIdx.x >> 6;
    const int er0  = lane & 31;     // A/D row pos; B/D col (hid); h col (k)
    const int half = lane >> 5;
    float* hl = (float*)(smem + 66 * 1024) + wave * (32 * 33);  // per-wave h

    // w1 B-fragment (16x32): lane l -> w1[(l>>5)*8+j][l&31]
    s16x8 w1f;
    #pragma unroll
    for (int j = 0; j < 8; j++) w1f[j] = bfs(w1[(half * 8 + j) * 32 + er0]);
    const float b1v = b1[er0];

    for (int tile = blockIdx.x * 16 + wave; tile < NT; tile += 4096) {
        const int B0  = tile * 32;
        const int pos = B0 + er0;
        const int pc  = pos < NE ? pos : NE - 1;
        const int src = srcs[pc];

        // x (bf16-pair rows): pair-cols [half*4,+4) and [8+half*4,+4)
        u32x4 xl4 = *(const u32x4*)(xpk + src * 16 + half * 4);
        u32x4 xh4 = *(const u32x4*)(xpk + src * 16 + 8 + half * 4);
        float xlo[8], xhi[8];
        #pragma unroll
        for (int q = 0; q < 4; q++) {
            xlo[2*q] = ulo(xl4[q]); xlo[2*q+1] = uhi(xl4[q]);
            xhi[2*q] = ulo(xh4[q]); xhi[2*q+1] = uhi(xh4[q]);
        }

        // ea A-fragment: one 16-B load (pre-packed in fragment order)
        s16x8 eaf = *(const s16x8*)(easp + (size_t)pc * 8 + half * 4);

        // h = relu(ea @ w1 + b1): D row=e, col=k=er0; stage through LDS
        f32x16 hc = {};
        hc = __builtin_amdgcn_mfma_f32_32x32x16_bf16(eaf, w1f, hc, 0, 0, 0);
        #pragma unroll
        for (int r = 0; r < 16; r++) {
            int e = (r & 3) + 8 * (r >> 2) + 4 * half;
            hl[e * 33 + er0] = fmaxf(hc[r] + b1v, 0.f);
        }

        f32x16 acc = {};
        const float* hrow = hl + er0 * 33;
        #pragma unroll 2
        for (int s2 = 0; s2 < 32; s2++) {
            float hk = hrow[s2];
            s16x8 alo, ahi;
            #pragma unroll
            for (int j = 0; j < 8; j++) alo[j] = bfs(hk * xlo[j]);
            #pragma unroll
            for (int j = 0; j < 8; j++) ahi[j] = bfs(hk * xhi[j]);
            s16x8 blo = *(const s16x8*)(sw2 + (2 * s2)     * 256 + lane * 4);
            s16x8 bhi = *(const s16x8*)(sw2 + (2 * s2 + 1) * 256 + lane * 4);
            acc = __builtin_amdgcn_mfma_f32_32x32x16_bf16(alo, blo, acc, 0, 0, 0);
            acc = __builtin_amdgcn_mfma_f32_32x32x16_bf16(ahi, bhi, acc, 0, 0, 0);
        }
        // b2 rows (h == 1): steps 64, 65
        {
            s16x8 alo, ahi;
            #pragma unroll
            for (int j = 0; j < 8; j++) alo[j] = bfs(xlo[j]);
            #pragma unroll
            for (int j = 0; j < 8; j++) ahi[j] = bfs(xhi[j]);
            s16x8 b64 = *(const s16x8*)(sw2 + 64 * 256 + lane * 4);
            s16x8 b65 = *(const s16x8*)(sw2 + 65 * 256 + lane * 4);
            acc = __builtin_amdgcn_mfma_f32_32x32x16_bf16(alo, b64, acc, 0, 0, 0);
            acc = __builtin_amdgcn_mfma_f32_32x32x16_bf16(ahi, b65, acc, 0, 0, 0);
        }

        // streamed store: D row r -> sorted position p; pack hid pair
        #pragma unroll
        for (int r = 0; r < 16; r++) {
            const int p  = B0 + (r & 3) + 8 * (r >> 2) + 4 * half;
            const float partner = __shfl_xor(acc[r], 1);
            if (!(er0 & 1) && p < NE) {
                unsigned pkv = (bf16r(partner) << 16) | bf16r(acc[r]);
                msgp[(size_t)p * 16 + (er0 >> 1)] = pkv;
            }
        }
    }
}

// ---------------------------------------------------------------------------
// K8: node kernel — contiguous gather of sorted msg run, mean, epilogue.
// ---------------------------------------------------------------------------
__global__ __launch_bounds__(256) void node_kernel(
    const float* __restrict__ x, const float* __restrict__ root,
    const float* __restrict__ bias_conv, const float* __restrict__ w3,
    const float* __restrict__ b3, const int* __restrict__ rowp,
    const unsigned* __restrict__ msgp, float* __restrict__ out)
{
    __shared__ float xs[8][32];
    __shared__ float ms[8][32];
    const int li = threadIdx.x >> 5, hid = threadIdx.x & 31;
    const int n = blockIdx.x * 8 + li;

    xs[li][hid] = x[n * 32 + hid];
    __syncthreads();

    float xr = 0.f;
    #pragma unroll
    for (int t = 0; t < 32; t++) xr += xs[li][t] * root[t * 32 + hid];

    const int r0 = rowp[n], r1 = rowp[n + 1];
    float m = 0.f;
    for (int p = r0; p < r1; ++p) {
        unsigned v = msgp[(size_t)p * 16 + (hid >> 1)];
        m += (hid & 1) ? uhi(v) : ulo(v);
    }
    float ic = 1.0f / (float)(r1 > r0 ? r1 - r0 : 1);
    m = m * ic + xr + bias_conv[hid];
    ms[li][hid] = m;
    __syncthreads();

    float o = b3[hid];
    #pragma unroll
    for (int t = 0; t < 32; t++) {
        o += xs[li][t] * w3[t * 32 + hid];
        o += ms[li][t] * w3[(32 + t) * 32 + hid];
    }
    out[n * 32 + hid] = fmaxf(o, 0.f);
}

// ---------------------------------------------------------------------------
extern "C" void kernel_launch(void* const* d_in, const int* in_sizes, int n_in,
                              void* d_out, int out_size, void* d_ws, size_t ws_size,
                              hipStream_t stream) {
    const float* x    = (const float*)d_in[0];
    const int*   ei   = (const int*)  d_in[1];
    const float* ea   = (const float*)d_in[2];
    const float* w1   = (const float*)d_in[3];
    const float* b1   = (const float*)d_in[4];
    const float* w2   = (const float*)d_in[5];
    const float* b2   = (const float*)d_in[6];
    const float* root = (const float*)d_in[7];
    const float* bc   = (const float*)d_in[8];
    const float* w3   = (const float*)d_in[9];
    const float* b3   = (const float*)d_in[10];

    char* ws = (char*)d_ws;
    unsigned* w2pk = (unsigned*)(ws + 0);
    int*      hist = (int*)(ws + 67584);
    int*      rowp = (int*)(ws + 267584);
    int*      off  = (int*)(ws + 467600);
    int*      blks = (int*)(ws + 667600);
    int*      srcs = (int*)(ws + 668624);
    unsigned* easp = (unsigned*)(ws + 1668688);
    unsigned* xpk  = (unsigned*)(ws + 9669200);
    unsigned* msgp = (unsigned*)(ws + 12869200);
    int*      tmp  = srcs;                       // scan scratch (pre-scatter)
    float*    out  = (float*)d_out;

    prep_kernel<<<3240, 256, 0, stream>>>(w2, b2, x, w2pk, xpk, hist);
    hist_kernel<<<977, 256, 0, stream>>>(ei, hist);
    scan_a<<<196, 256, 0, stream>>>(hist, tmp, blks);
    scan_b<<<1, 256, 0, stream>>>(blks);
    addback<<<196, 256, 0, stream>>>(hist, tmp, blks, rowp, off);
    scatter_kernel<<<977, 256, 0, stream>>>(ei, ea, off, srcs, easp);

    const int lds_bytes = 66 * 1024 + 16 * 32 * 33 * 4;   // 135168
    hipFuncSetAttribute((const void*)edge_kernel,
                        hipFuncAttributeMaxDynamicSharedMemorySize, lds_bytes);
    edge_kernel<<<256, 1024, lds_bytes, stream>>>(xpk, srcs, easp, w1, b1,
                                                  w2pk, msgp);

    node_kernel<<<NN / 8, 256, 0, stream>>>(x, root, bc, w3, b3, rowp, msgp, out);
}